// Round 9
// baseline (375.376 us; speedup 1.0000x reference)
//
#include <hip/hip_runtime.h>
#include <math.h>

#define SEQ   2048
#define NHEAD 16
#define HD    64
#define BSZ   2
#define MTOT  (BSZ*SEQ)   // 4096

#define LOG2E    1.4426950408889634f
#define C_SCALE  0.18033688011112043f    // 0.125 * log2(e)
#define C_MOFF  -23.083120654223414f     // -16 * log2(e)

typedef __bf16 bf16x8 __attribute__((ext_vector_type(8)));
typedef short  s16x8  __attribute__((ext_vector_type(8)));
typedef short  s16x4  __attribute__((ext_vector_type(4)));
typedef float  f32x4  __attribute__((ext_vector_type(4)));

// round-to-nearest-even fp32 -> bf16 (raw short)
__device__ __forceinline__ short f2bf(float x) {
    unsigned u = __builtin_bit_cast(unsigned, x);
    u = (u + 0x7fffu + ((u >> 16) & 1u)) >> 16;
    return (short)u;
}
__device__ __forceinline__ float bf2f(short h) {
    unsigned u = ((unsigned)(unsigned short)h) << 16;
    return __builtin_bit_cast(float, u);
}

// native v_exp_f32 (2^x), no OCML fixup path
__device__ __forceinline__ float fast_exp2(float x) {
    return __builtin_amdgcn_exp2f(x);
}

// async global->LDS 16B: dest = wave-uniform lds base + lane*16
__device__ __forceinline__ void gl_lds16(const short* g, short* l) {
    __builtin_amdgcn_global_load_lds(
        (const __attribute__((address_space(1))) unsigned int*)g,
        (__attribute__((address_space(3))) unsigned int*)l, 16, 0, 0);
}

// ---------------------------------------------------------------------------
// Transpose+split one 32x32 tile: W[K,N] fp32 -> Th/Tl [N,K] bf16 hi/lo
// ---------------------------------------------------------------------------
__device__ __forceinline__ void tsplit_tile(const float* __restrict__ W,
    short* __restrict__ Th, short* __restrict__ Tl,
    int K, int N, int k0, int n0, float (*T)[33], int t)
{
    {
        const int kl = t >> 3;
        const int nl = (t & 7) * 4;
        const float4 v = *(const float4*)&W[(size_t)(k0 + kl) * N + n0 + nl];
        T[nl + 0][kl] = v.x; T[nl + 1][kl] = v.y;
        T[nl + 2][kl] = v.z; T[nl + 3][kl] = v.w;
    }
    __syncthreads();
    {
        const int nl = t >> 3;
        const int kl = (t & 7) * 4;
        s16x4 h, l;
        #pragma unroll
        for (int c = 0; c < 4; ++c) {
            const float x = T[nl][kl + c];
            const short hb = f2bf(x);
            h[c] = hb;
            l[c] = f2bf(x - bf2f(hb));
        }
        const size_t o = (size_t)(n0 + nl) * K + k0 + kl;
        *(s16x4*)&Th[o] = h;
        *(s16x4*)&Tl[o] = l;
    }
}

// ---------------------------------------------------------------------------
// prep: [0,1024) seq -> seqh (bf16 hi only);
//       [1024,4096) Wqkv tsplit; [4096,6144) W1 tsplit.
// ---------------------------------------------------------------------------
__global__ __launch_bounds__(256)
void prep_kernel(const float* __restrict__ seq, short* __restrict__ seqh,
                 const float* __restrict__ Wqkv, short* __restrict__ WtQh, short* __restrict__ WtQl,
                 const float* __restrict__ W1, short* __restrict__ Wt1h, short* __restrict__ Wt1l)
{
    __shared__ float T[32][33];
    const int t = threadIdx.x;
    const int bid = blockIdx.x;
    if (bid < 1024) {
        const size_t base = (size_t)bid * 4096 + (size_t)t * 16;
        #pragma unroll
        for (int c = 0; c < 4; ++c) {
            const float4 v = *(const float4*)&seq[base + c * 4];
            s16x4 h;
            h[0] = f2bf(v.x); h[1] = f2bf(v.y); h[2] = f2bf(v.z); h[3] = f2bf(v.w);
            *(s16x4*)&seqh[base + c * 4] = h;
        }
    } else if (bid < 4096) {
        const int idx = bid - 1024;
        tsplit_tile(Wqkv, WtQh, WtQl, 1024, 3072, (idx & 31) * 32, (idx >> 5) * 32, T, t);
    } else {
        const int idx = bid - 4096;
        tsplit_tile(W1, Wt1h, Wt1l, 1024, 2048, (idx & 31) * 32, (idx >> 5) * 32, T, t);
    }
}

// ---------------------------------------------------------------------------
// util: [0,4096) transpose Vnat[4096][1024] -> Vth[1024][4096]; [4096,6144) W2 tsplit.
// ---------------------------------------------------------------------------
__global__ __launch_bounds__(256)
void util_kernel(const short* __restrict__ Vnat, short* __restrict__ Vth,
                 const float* __restrict__ W2, short* __restrict__ Wt2h, short* __restrict__ Wt2l)
{
    __shared__ float T[32][33];
    const int t = threadIdx.x;
    const int bid = blockIdx.x;
    if (bid < 4096) {
        short (*TT)[36] = (short(*)[36])T;
        const int r0 = (bid & 127) * 32;
        const int f0 = (bid >> 7) * 32;
        {
            const int rl = t >> 3;
            const int fl = (t & 7) * 4;
            const s16x4 v = *(const s16x4*)&Vnat[(size_t)(r0 + rl) * 1024 + f0 + fl];
            TT[fl + 0][rl] = v[0]; TT[fl + 1][rl] = v[1];
            TT[fl + 2][rl] = v[2]; TT[fl + 3][rl] = v[3];
        }
        __syncthreads();
        {
            const int fl = t >> 3;
            const int rl = (t & 7) * 4;
            s16x4 o;
            o[0] = TT[fl][rl + 0]; o[1] = TT[fl][rl + 1];
            o[2] = TT[fl][rl + 2]; o[3] = TT[fl][rl + 3];
            *(s16x4*)&Vth[(size_t)(f0 + fl) * 4096 + r0 + rl] = o;
        }
    } else {
        const int idx = bid - 4096;
        tsplit_tile(W2, Wt2h, Wt2l, 2048, 1024, (idx & 63) * 32, (idx >> 6) * 32, T, t);
    }
}

// ---------------------------------------------------------------------------
// split MFMA GEMM v4. A single bf16 (2-term: Ah*Bh + Ah*Bl), B hi/lo.
// OMODE: 0 fp32 out, 1 split hi/lo out, 2 hi-only out. ACT 1: SiLU.
// VT=1 (QKV): cols>=2048 -> Vnat bf16 natural store.
// Block 128 x NB, BK=32, 4 waves, global_load_lds staging, XOR swizzle.
// ---------------------------------------------------------------------------
template<int ACT, int OMODE, int VT, int NB>
__global__ __launch_bounds__(256, 2)
void gemm2(const short* __restrict__ Ahg,
           const short* __restrict__ Bhg, const short* __restrict__ Blg,
           const float* __restrict__ bias,
           float* __restrict__ Cf, short* __restrict__ Chg, short* __restrict__ Clg,
           short* __restrict__ Vng,
           int M, int N, int K, int NOUT)
{
    constexpr int NJ = NB / 32;
    __shared__ short AhL[128 * 32];
    __shared__ short BhL[NB * 32];
    __shared__ short BlL[NB * 32];

    const int t    = threadIdx.x;
    const int m0   = blockIdx.y * 128;
    const int n0   = blockIdx.x * NB;
    const int wave = t >> 6;
    const int lane = t & 63;
    const int r    = lane & 15;
    const int qd   = lane >> 4;
    const int wm   = (wave & 1) * 64;
    const int wn   = (wave >> 1) * (NB / 2);

    f32x4 acc[4][NJ];
    #pragma unroll
    for (int i = 0; i < 4; ++i)
        #pragma unroll
        for (int j = 0; j < NJ; ++j) acc[i][j] = (f32x4){0.f, 0.f, 0.f, 0.f};

    for (int k0 = 0; k0 < K; k0 += 32) {
        __syncthreads();
        #pragma unroll
        for (int s = 0; s < 2; ++s) {
            const int p    = wave * 2 + s;
            const int srow = p * 16 + (lane >> 2);
            const int sg   = (lane & 3) ^ ((srow >> 1) & 3);
            const size_t ga = (size_t)(m0 + srow) * K + k0 + sg * 8;
            gl_lds16(&Ahg[ga], &AhL[p * 512]);
        }
        #pragma unroll
        for (int s = 0; s < NB / 64; ++s) {
            const int p    = wave * (NB / 64) + s;
            const int srow = p * 16 + (lane >> 2);
            const int sg   = (lane & 3) ^ ((srow >> 1) & 3);
            const size_t gb = (size_t)(n0 + srow) * K + k0 + sg * 8;
            gl_lds16(&Bhg[gb], &BhL[p * 512]);
            gl_lds16(&Blg[gb], &BlL[p * 512]);
        }
        __syncthreads();

        bf16x8 afh[4], bfh[NJ], bfl[NJ];
        #pragma unroll
        for (int i = 0; i < 4; ++i) {
            const int row = wm + i * 16 + r;
            const int oa = row * 32 + ((qd ^ ((row >> 1) & 3)) * 8);
            afh[i] = __builtin_bit_cast(bf16x8, *(const s16x8*)&AhL[oa]);
        }
        #pragma unroll
        for (int j = 0; j < NJ; ++j) {
            const int row = wn + j * 16 + r;
            const int ob = row * 32 + ((qd ^ ((row >> 1) & 3)) * 8);
            bfh[j] = __builtin_bit_cast(bf16x8, *(const s16x8*)&BhL[ob]);
            bfl[j] = __builtin_bit_cast(bf16x8, *(const s16x8*)&BlL[ob]);
        }

        #pragma unroll
        for (int i = 0; i < 4; ++i)
            #pragma unroll
            for (int j = 0; j < NJ; ++j) {
                acc[i][j] = __builtin_amdgcn_mfma_f32_16x16x32_bf16(afh[i], bfh[j], acc[i][j], 0, 0, 0);
                acc[i][j] = __builtin_amdgcn_mfma_f32_16x16x32_bf16(afh[i], bfl[j], acc[i][j], 0, 0, 0);
            }
    }

    // epilogue: C/D layout col=lane&15, row=quad*4+g
    #pragma unroll
    for (int i = 0; i < 4; ++i)
        #pragma unroll
        for (int j = 0; j < NJ; ++j) {
            const int col = n0 + wn + j * 16 + r;
            if (VT && col >= 2048) {
                #pragma unroll
                for (int g = 0; g < 4; ++g) {
                    const int row = m0 + wm + i * 16 + qd * 4 + g;
                    Vng[(size_t)row * 1024 + (col - 2048)] = f2bf(acc[i][j][g]);
                }
            } else {
                const float bv = bias ? bias[col] : 0.f;
                #pragma unroll
                for (int g = 0; g < 4; ++g) {
                    const int row = m0 + wm + i * 16 + qd * 4 + g;
                    float x = acc[i][j][g] + bv;
                    if (ACT == 1) x = x / (1.0f + __expf(-x));
                    if (OMODE == 0) {
                        Cf[(size_t)row * NOUT + col] = x;
                    } else if (OMODE == 1) {
                        const short hb = f2bf(x);
                        Chg[(size_t)row * NOUT + col] = hb;
                        Clg[(size_t)row * NOUT + col] = f2bf(x - bf2f(hb));
                    } else {
                        Chg[(size_t)row * NOUT + col] = f2bf(x);
                    }
                }
            }
        }
}

// ---------------------------------------------------------------------------
// MFMA flash attention v5: Q single-bf16 (S = qh*kh + qh*kl, K keeps hi/lo);
// mask rescale folded into load; native v_exp_f32 softmax; output hi-only.
// K/V double-buffered via global_load_lds, one barrier per tile.
// ---------------------------------------------------------------------------
__global__ __launch_bounds__(256, 2)
void attn_mfma3(const short* __restrict__ Xh, const short* __restrict__ Xl,
                const short* __restrict__ Vth, const float* __restrict__ mask,
                short* __restrict__ atth)
{
    __shared__ short KhL[2 * 64 * 64];
    __shared__ short KlL[2 * 64 * 64];
    __shared__ short VhL[2 * 64 * 64];
    __shared__ short PhL[128 * 64];

    const int t    = threadIdx.x;
    const int lane = t & 63;
    const int w    = t >> 6;
    const int r    = lane & 15;
    const int qd   = lane >> 4;
    const int b    = blockIdx.x >> 4;
    const int h    = blockIdx.x & 15;
    const int q0   = blockIdx.y * 128;

    const int srow0 = (lane >> 3);
    const int sgx   = lane & 7;

    // Q fragments (hi only)
    bf16x8 qh[2][2];
    #pragma unroll
    for (int i = 0; i < 2; ++i) {
        const size_t qoff = (size_t)(b * SEQ + q0 + w * 32 + i * 16 + r) * 2048 + h * 64;
        #pragma unroll
        for (int ks = 0; ks < 2; ++ks)
            qh[i][ks] = __builtin_bit_cast(bf16x8, *(const s16x8*)&Xh[qoff + ks * 32 + qd * 8]);
    }

    s16x8 ones_s;
    #pragma unroll
    for (int c = 0; c < 8; ++c) ones_s[c] = (short)0x3F80;
    const bf16x8 ones = __builtin_bit_cast(bf16x8, ones_s);

    f32x4 O[2][4], Lac[2];
    #pragma unroll
    for (int i = 0; i < 2; ++i) {
        Lac[i] = (f32x4){0.f, 0.f, 0.f, 0.f};
        #pragma unroll
        for (int j = 0; j < 4; ++j) O[i][j] = (f32x4){0.f, 0.f, 0.f, 0.f};
    }

    auto stage = [&](int kt, int buf) {
        const int k0   = kt * 64;
        const int tok0 = b * SEQ + k0;
        const int bo   = buf * 4096;
        #pragma unroll
        for (int s = 0; s < 2; ++s) {
            const int p    = w * 2 + s;
            const int srow = p * 8 + srow0;
            const int sg   = sgx ^ (srow & 7);
            const size_t gk = (size_t)(tok0 + srow) * 2048 + 1024 + h * 64 + sg * 8;
            gl_lds16(&Xh[gk], &KhL[bo + p * 512]);
            gl_lds16(&Xl[gk], &KlL[bo + p * 512]);
            const size_t gv = (size_t)(h * 64 + srow) * 4096 + (size_t)b * SEQ + k0 + sg * 8;
            gl_lds16(&Vth[gv], &VhL[bo + p * 512]);
        }
    };

    stage(0, 0);

    for (int kt = 0; kt < SEQ / 64; ++kt) {
        const int cur = kt & 1;
        const int k0  = kt * 64;

        __syncthreads();
        if (kt + 1 < SEQ / 64) stage(kt + 1, 1 - cur);

        // mask load + fold rescale: m' = m*log2e - 16*log2e
        float mreg[2][4][4];
        #pragma unroll
        for (int i = 0; i < 2; ++i)
            #pragma unroll
            for (int g = 0; g < 4; ++g) {
                const size_t mrow = (size_t)(q0 + w * 32 + i * 16 + qd * 4 + g) * SEQ + k0;
                #pragma unroll
                for (int j = 0; j < 4; ++j)
                    mreg[i][g][j] = fmaf(mask[mrow + j * 16 + r], LOG2E, C_MOFF);
            }

        const int co = cur * 4096;
        f32x4 S[2][4];
        #pragma unroll
        for (int i = 0; i < 2; ++i)
            #pragma unroll
            for (int j = 0; j < 4; ++j) S[i][j] = (f32x4){0.f, 0.f, 0.f, 0.f};
        #pragma unroll
        for (int ks = 0; ks < 2; ++ks) {
            bf16x8 kfh[4], kfl[4];
            #pragma unroll
            for (int j = 0; j < 4; ++j) {
                const int row = j * 16 + r;
                const int off = co + row * 64 + (((ks * 4 + qd) ^ (row & 7)) * 8);
                kfh[j] = __builtin_bit_cast(bf16x8, *(const s16x8*)&KhL[off]);
                kfl[j] = __builtin_bit_cast(bf16x8, *(const s16x8*)&KlL[off]);
            }
            #pragma unroll
            for (int i = 0; i < 2; ++i)
                #pragma unroll
                for (int j = 0; j < 4; ++j) {
                    S[i][j] = __builtin_amdgcn_mfma_f32_16x16x32_bf16(qh[i][ks], kfh[j], S[i][j], 0, 0, 0);
                    S[i][j] = __builtin_amdgcn_mfma_f32_16x16x32_bf16(qh[i][ks], kfl[j], S[i][j], 0, 0, 0);
                }
        }

        // p = exp2(s * 0.125*log2e + m')  — native v_exp_f32
        #pragma unroll
        for (int i = 0; i < 2; ++i)
            #pragma unroll
            for (int j = 0; j < 4; ++j)
                #pragma unroll
                for (int g = 0; g < 4; ++g)
                    S[i][j][g] = fast_exp2(fmaf(S[i][j][g], C_SCALE, mreg[i][g][j]));

        #pragma unroll
        for (int i = 0; i < 2; ++i)
            #pragma unroll
            for (int j = 0; j < 4; ++j)
                #pragma unroll
                for (int g = 0; g < 4; ++g) {
                    const int prow = w * 32 + i * 16 + qd * 4 + g;
                    const int gr   = (j * 2 + (r >> 3)) ^ ((prow >> 1) & 7);
                    PhL[prow * 64 + gr * 8 + (r & 7)] = f2bf(S[i][j][g]);
                }

        #pragma unroll
        for (int ks = 0; ks < 2; ++ks) {
            bf16x8 pfh[2], vfh[4];
            #pragma unroll
            for (int i = 0; i < 2; ++i) {
                const int row = w * 32 + i * 16 + r;
                pfh[i] = __builtin_bit_cast(bf16x8,
                    *(const s16x8*)&PhL[row * 64 + (((ks * 4 + qd) ^ ((row >> 1) & 7)) * 8)]);
            }
            #pragma unroll
            for (int j = 0; j < 4; ++j) {
                const int row = j * 16 + r;
                vfh[j] = __builtin_bit_cast(bf16x8,
                    *(const s16x8*)&VhL[co + row * 64 + (((ks * 4 + qd) ^ (row & 7)) * 8)]);
            }
            #pragma unroll
            for (int i = 0; i < 2; ++i) {
                Lac[i] = __builtin_amdgcn_mfma_f32_16x16x32_bf16(pfh[i], ones, Lac[i], 0, 0, 0);
                #pragma unroll
                for (int j = 0; j < 4; ++j)
                    O[i][j] = __builtin_amdgcn_mfma_f32_16x16x32_bf16(pfh[i], vfh[j], O[i][j], 0, 0, 0);
            }
        }
    }

    #pragma unroll
    for (int i = 0; i < 2; ++i)
        #pragma unroll
        for (int g = 0; g < 4; ++g) {
            const float inv = 1.0f / Lac[i][g];
            const size_t row = (size_t)(b * SEQ + q0 + w * 32 + i * 16 + qd * 4 + g);
            #pragma unroll
            for (int j = 0; j < 4; ++j)
                atth[row * 1024 + h * 64 + j * 16 + r] = f2bf(O[i][j][g] * inv);
        }
}

// ---------------------------------------------------------------------------
extern "C" void kernel_launch(void* const* d_in, const int* in_sizes, int n_in,
                              void* d_out, int out_size, void* d_ws, size_t ws_size,
                              hipStream_t stream)
{
    const float* seq  = (const float*)d_in[0];
    const float* mask = (const float*)d_in[1];
    const float* Wqkv = (const float*)d_in[2];
    const float* W1   = (const float*)d_in[3];
    const float* b1   = (const float*)d_in[4];
    const float* W2   = (const float*)d_in[5];
    const float* b2   = (const float*)d_in[6];
    float* out = (float*)d_out;

    // ws (64 MiB): Xh[0,16) Xl[16,32) Vnat[32,40) Wt1[40,48) WtQ[48,60)
    //   after QKV: Vth[48,56) Wt2[56,64);  after attn: hidh[0,16)
    // d_out (16 MiB): seqh[0,8) -> atth[0,8) -> out[0,16)
    const size_t MiB = 1048576;
    char* B = (char*)d_ws;
    short* Xh   = (short*)(B + 0);
    short* Xl   = (short*)(B + 16 * MiB);
    short* Vnat = (short*)(B + 32 * MiB);
    short* Wt1h = (short*)(B + 40 * MiB);
    short* Wt1l = (short*)(B + 44 * MiB);
    short* WtQh = (short*)(B + 48 * MiB);
    short* WtQl = (short*)(B + 54 * MiB);
    short* Vth  = (short*)(B + 48 * MiB);
    short* Wt2h = (short*)(B + 56 * MiB);
    short* Wt2l = (short*)(B + 60 * MiB);
    short* hidh = (short*)(B + 0);

    short* seqh = (short*)d_out;
    short* atth = (short*)d_out;

    // P0: seq hi-split + Wqkv/W1 transpose-splits
    prep_kernel<<<6144, 256, 0, stream>>>(seq, seqh, Wqkv, WtQh, WtQl, W1, Wt1h, Wt1l);

    // P1: QKV (2-term) — Q|K split -> Xh/Xl, V natural bf16 -> Vnat
    gemm2<0, 1, 1, 128><<<dim3(3072 / 128, MTOT / 128), 256, 0, stream>>>(
        seqh, WtQh, WtQl, nullptr,
        nullptr, Xh, Xl, Vnat, MTOT, 3072, 1024, 2048);

    // P2: V transpose + W2 split
    util_kernel<<<6144, 256, 0, stream>>>(Vnat, Vth, W2, Wt2h, Wt2l);

    // P3: flash attention -> atth (hi only) in d_out
    attn_mfma3<<<dim3(BSZ * NHEAD, SEQ / 128), 256, 0, stream>>>(Xh, Xl, Vth, mask, atth);

    // P4: FFN1 + SiLU (2-term) -> hidh
    gemm2<1, 2, 0, 128><<<dim3(2048 / 128, MTOT / 128), 256, 0, stream>>>(
        atth, Wt1h, Wt1l, b1,
        nullptr, hidh, nullptr, nullptr, MTOT, 2048, 1024, 2048);

    // P5: FFN2 + bias (2-term) -> out
    gemm2<0, 0, 0, 64><<<dim3(1024 / 64, MTOT / 128), 256, 0, stream>>>(
        hidh, Wt2h, Wt2l, b2,
        out, nullptr, nullptr, nullptr, MTOT, 1024, 2048, 1024);
}